// Round 11
// baseline (1586.911 us; speedup 1.0000x reference)
//
#include <hip/hip_runtime.h>

#define T_STEPS 512
#define BATCH   64
#define IN_SZ   32
#define AD      32
#define INNER   256
#define PROJ    224
#define HID     512
#define SENTW   0x7F7F7F7Fu   // bf16 0x7F7F = 3.3e38; impossible for |h|<1 outputs
#define SENT64  0x7F7F7F7F7F7F7F7FULL
#define DEP     16            // ring depth (slots per batch-group)
#define RST     6             // producer reset distance (slots ahead)
#define SLOTW   4096          // u32 words per 16KB slot

typedef __attribute__((ext_vector_type(8))) short short8;
typedef __attribute__((ext_vector_type(4))) float f32x4;

static __device__ __forceinline__ unsigned short f2bf(float f) {
  unsigned int u = __float_as_uint(f);
  u += 0x7FFFu + ((u >> 16) & 1u);
  return (unsigned short)(u >> 16);
}
static __device__ __forceinline__ float sigmoidf_(float x) { return 1.f / (1.f + __expf(-x)); }
static __device__ __forceinline__ float tanhf_(float x) {
  float e = __expf(-2.f * fabsf(x));
  float r = (1.f - e) / (1.f + e);
  return x < 0.f ? -r : r;
}

// ---------------- kernel A: x = [relu(in_w@state+in_b) | emb[idx]] bf16, [t][b][256]
__global__ __launch_bounds__(256) void k_prep(
    const float* __restrict__ ws_in, const int* __restrict__ act_idx,
    const float* __restrict__ emb, const float* __restrict__ in_w,
    const float* __restrict__ in_b, unsigned short* __restrict__ x_bf)
{
  int t = blockIdx.x;
  int tid = threadIdx.x;
  __shared__ float st[BATCH * IN_SZ];
  __shared__ int ai[BATCH];
  for (int i = tid; i < BATCH * IN_SZ; i += 256) {
    int b = i >> 5, k = i & 31;
    st[i] = ws_in[((size_t)b * T_STEPS + t) * IN_SZ + k];
  }
  if (tid < BATCH) ai[tid] = act_idx[tid * T_STEPS + t];
  __syncthreads();
  if (tid < PROJ) {
    float w[IN_SZ];
    const float* wrow = in_w + tid * IN_SZ;
#pragma unroll
    for (int k = 0; k < IN_SZ; ++k) w[k] = wrow[k];
    float bb = in_b[tid];
    for (int b = 0; b < BATCH; ++b) {
      float acc = bb;
      const float* sb = st + b * IN_SZ;
#pragma unroll
      for (int k = 0; k < IN_SZ; ++k) acc += w[k] * sb[k];
      x_bf[((size_t)t * BATCH + b) * INNER + tid] = f2bf(fmaxf(acc, 0.f));
    }
  } else {
    int j = tid - PROJ;
    for (int b = 0; b < BATCH; ++b)
      x_bf[((size_t)t * BATCH + b) * INNER + tid] = f2bf(emb[ai[b] * AD + j]);
  }
}

// ---------------- helpers ----------------
static __device__ __forceinline__ short8 bfrag_load(const float* __restrict__ w, int stride, int row, int k0) {
  const float* p = w + (size_t)row * stride + k0;
  f32x4 a = *reinterpret_cast<const f32x4*>(p);
  f32x4 b = *reinterpret_cast<const f32x4*>(p + 4);
  short8 r;
  r[0] = (short)f2bf(a[0]); r[1] = (short)f2bf(a[1]); r[2] = (short)f2bf(a[2]); r[3] = (short)f2bf(a[3]);
  r[4] = (short)f2bf(b[0]); r[5] = (short)f2bf(b[1]); r[6] = (short)f2bf(b[2]); r[7] = (short)f2bf(b[3]);
  return r;
}

struct Frag64 { unsigned long long u[8]; };   // this lane's 4 k-chunks x 16B
union FU2 { unsigned long long u[2]; short8 s; };

// load this lane's 64B (4 chunks at 1KB stride) via agent-scope relaxed atomics
static __device__ __forceinline__ void ld64(const unsigned long long* q, Frag64& f) {
#pragma unroll
  for (int kk = 0; kk < 4; ++kk) {
    f.u[kk * 2]     = __hip_atomic_load(q + kk * 128,     __ATOMIC_RELAXED, __HIP_MEMORY_SCOPE_AGENT);
    f.u[kk * 2 + 1] = __hip_atomic_load(q + kk * 128 + 1, __ATOMIC_RELAXED, __HIP_MEMORY_SCOPE_AGENT);
  }
}
static __device__ __forceinline__ bool fragok(const Frag64& f) {
  bool ok = true;
#pragma unroll
  for (int i = 0; i < 8; ++i)
    ok = ok & ((unsigned)(f.u[i] >> 32) != SENTW) & ((unsigned)f.u[i] != SENTW);
  return ok;
}
// staggered double-buffer poll: two in-flight sample batches ~RTT/2 apart
static __device__ __forceinline__ Frag64 poll_one(const unsigned long long* q) {
  Frag64 fa, fb;
  ld64(q, fa);
  __builtin_amdgcn_s_sleep(14);      // ~900 cycles ~ RTT/2 stagger
  ld64(q, fb);
  while (true) {
    if (__all((int)fragok(fa))) return fa;
    ld64(q, fa);
    if (__all((int)fragok(fb))) return fb;
    ld64(q, fb);
  }
}
// joint staggered poll of two rings (L1): both must be valid; single detect for the later
static __device__ __forceinline__ void poll_two(const unsigned long long* qa, const unsigned long long* qb,
                                                Frag64& fa, Frag64& fb) {
  Frag64 ga, gb;
  ld64(qa, fa); ld64(qb, fb);
  __builtin_amdgcn_s_sleep(14);
  ld64(qa, ga); ld64(qb, gb);
  while (true) {
    if (__all((int)(fragok(fa) & fragok(fb)))) return;
    ld64(qa, fa); ld64(qb, fb);
    if (__all((int)(fragok(ga) & fragok(gb)))) { fa = ga; fb = gb; return; }
    ld64(qa, ga); ld64(qb, gb);
  }
}

static __device__ __forceinline__ void mfma4(const Frag64& f, const short8* wf, f32x4* acc) {
#pragma unroll
  for (int kk = 0; kk < 4; ++kk) {
    FU2 u; u.u[0] = f.u[kk * 2]; u.u[1] = f.u[kk * 2 + 1];
#pragma unroll
    for (int g = 0; g < 4; ++g)
      acc[g] = __builtin_amdgcn_mfma_f32_16x16x32_bf16(u.s, wf[g * 4 + kk], acc[g], 0, 0, 0);
  }
}

static __device__ __forceinline__ void st_agent(unsigned int* p, unsigned int v) {
  __hip_atomic_store(p, v, __ATOMIC_RELAXED, __HIP_MEMORY_SCOPE_AGENT);
}
static __device__ __forceinline__ void st_agent64(unsigned long long* p, unsigned long long v) {
  __hip_atomic_store(p, v, __ATOMIC_RELAXED, __HIP_MEMORY_SCOPE_AGENT);
}
static __device__ __forceinline__ size_t slotw(int bg, int d) { return ((size_t)(bg * DEP + d)) * SLOTW; }

// ---------------- persistent 2-layer LSTM ----------------
// R7 proven skeleton: 256 blocks; xg=blockIdx&7: layer=xg>=4, bg=xg&3; blk=blockIdx>>3
// owns hid [blk*16,+16). ALL cross-block traffic agent-scope data-as-flag sentinel rings
// (DEP 16, producer resets +6, zero drains); L1 consumption flags every 2 steps; L0 reuse
// guard every 4 (lag<=8 <= DEP-RST-1=9). R11: staggered dual-buffer polls (sampling RTT/2),
// u64-packed publishes, L0 speculative pre-poll, R7 conflict-free spart layout.
template<int L>
static __device__ void lstm_body(
    const unsigned short* __restrict__ x_bf,
    const float* __restrict__ wih, const float* __restrict__ whh,
    const float* __restrict__ bih, const float* __restrict__ bhh,
    unsigned int* __restrict__ h0w, unsigned int* __restrict__ h1w,
    float* __restrict__ h1fin, unsigned int* __restrict__ flags,
    int bg, int blk, float* __restrict__ spart)
{
  constexpr int KI = (L == 0) ? 2 : 4;

  const int tid  = threadIdx.x;
  const int lane = tid & 63;
  const int wv   = tid >> 6;
  const int q    = lane >> 4;
  const int ln   = lane & 15;
  const int hid0 = blk << 4;
  const int m    = tid >> 4;
  const int n    = tid & 15;
  // consumer u64 base: chunk kk at +kk*128 u64 (1KB); block-major slot layout
  const int cb64 = (wv * 8 + (q >> 1)) * 64 + ln * 4 + (q & 1) * 2;

  float bias[4];
#pragma unroll
  for (int g = 0; g < 4; ++g)
    bias[g] = bih[g * HID + hid0 + n] + bhh[g * HID + hid0 + n];

  short8 fih[4 * KI];
#pragma unroll
  for (int g = 0; g < 4; ++g)
#pragma unroll
    for (int kk = 0; kk < KI; ++kk)
      fih[g * KI + kk] = bfrag_load(wih, (L == 0) ? INNER : HID,
                                    g * HID + hid0 + ln, (wv * KI + kk) * 32 + q * 8);
  short8 fhh[16];
#pragma unroll
  for (int g = 0; g < 4; ++g)
#pragma unroll
    for (int kk = 0; kk < 4; ++kk)
      fhh[g * 4 + kk] = bfrag_load(whh, HID, g * HID + hid0 + ln, (wv * 4 + kk) * 32 + q * 8);

  // producer u64 slot (lanes with n%4==0 store 4 packed h values)
  const int wo64 = blk * 64 + m * 4 + (n >> 2);
  float c_state = 0.f;

  for (int t = 0; t < T_STEPS; ++t) {
    f32x4 acc[4];
#pragma unroll
    for (int g = 0; g < 4; ++g) acc[g] = (f32x4){0.f, 0.f, 0.f, 0.f};

    if constexpr (L == 0) {
      // speculative pre-poll: issue h0[t-1] loads NOW; verify after x-MFMAs
      const unsigned long long* hq = reinterpret_cast<const unsigned long long*>(
          h0w + slotw(bg, (t - 1) & (DEP - 1))) + cb64;
      Frag64 f0;
      if (t > 0) ld64(hq, f0);

      // x-side (static, cached) — overlaps the in-flight h loads
      const unsigned short* xr = x_bf + ((size_t)t * BATCH + bg * 16 + ln) * INNER + q * 8;
#pragma unroll
      for (int kk = 0; kk < KI; ++kk) {
        short8 xa = *reinterpret_cast<const short8*>(xr + (wv * KI + kk) * 32);
#pragma unroll
        for (int g = 0; g < 4; ++g)
          acc[g] = __builtin_amdgcn_mfma_f32_16x16x32_bf16(xa, fih[g * KI + kk], acc[g], 0, 0, 0);
      }
      // ring-reuse guard vs layer 1 (every 4 steps)
      if ((t & 3) == 0 && t >= 8) {
        const unsigned int* fp = flags + (bg * 32 + (lane & 31)) * 32;
        unsigned int tgt = (unsigned)(t - 4);
        while (true) {
          unsigned int v = __hip_atomic_load(fp, __ATOMIC_RELAXED, __HIP_MEMORY_SCOPE_AGENT);
          if (__all((int)(v >= tgt))) break;
          __builtin_amdgcn_s_sleep(1);
        }
        asm volatile("" ::: "memory");
      }
      if (t > 0) {
        if (!__all((int)fragok(f0))) f0 = poll_one(hq);   // staggered poll on miss
        mfma4(f0, fhh, acc);
      }
    } else {
      if (t > 0) {  // joint staggered poll: h1[t-1] (self) + h0[t] (cross)
        Frag64 fa, fb;
        poll_two(reinterpret_cast<const unsigned long long*>(h1w + slotw(bg, (t - 1) & (DEP - 1))) + cb64,
                 reinterpret_cast<const unsigned long long*>(h0w + slotw(bg, t & (DEP - 1))) + cb64, fa, fb);
        mfma4(fa, fhh, acc);
        mfma4(fb, fih, acc);
      } else {
        Frag64 fb = poll_one(reinterpret_cast<const unsigned long long*>(h0w + slotw(bg, 0)) + cb64);
        mfma4(fb, fih, acc);
      }
    }

    // K-split partial exchange (R7 layout: XOR swizzle, conflict-free; dbuf, 1 barrier)
    float* sp_w = spart + (t & 1) * 4096;
#pragma unroll
    for (int g = 0; g < 4; ++g)
#pragma unroll
      for (int r = 0; r < 4; ++r)
        sp_w[(((wv * 4 + g) * 4 + r) * 4 + (q ^ r)) * 16 + ln] = acc[g][r];
    __syncthreads();

    if constexpr (L == 1) {  // consumption flag (h0[t] loads completed before barrier)
      if ((t & 1) == 1 && tid == 0)
        st_agent(flags + (bg * 32 + blk) * 32, (unsigned)(t + 1));
    }

    float gate[4];
#pragma unroll
    for (int g = 0; g < 4; ++g) {
      float s = bias[g];
#pragma unroll
      for (int w2 = 0; w2 < 4; ++w2)
        s += sp_w[(((w2 * 4 + g) * 4 + (m & 3)) * 4 + ((m >> 2) ^ (m & 3))) * 16 + n];
      gate[g] = s;
    }
    float gi = sigmoidf_(gate[0]);
    float gf = sigmoidf_(gate[1]);
    float gc = tanhf_(gate[2]);
    float go = sigmoidf_(gate[3]);
    float c_new = gf * c_state + gi * gc;
    float h = go * tanhf_(c_new);

    // publish FIRST (h-store on the critical path), bookkeeping after
    float hp = __shfl_xor(h, 1);
    unsigned int wword = (unsigned)f2bf(h) | ((unsigned)f2bf(hp) << 16);
    unsigned int wy = __shfl_down(wword, 2);
    unsigned long long dw = (unsigned long long)wword | ((unsigned long long)wy << 32);
    if constexpr (L == 0) {
      if (!(n & 3)) {
        st_agent64(reinterpret_cast<unsigned long long*>(h0w + slotw(bg, t & (DEP - 1))) + wo64, dw);
        st_agent64(reinterpret_cast<unsigned long long*>(h0w + slotw(bg, (t + RST) & (DEP - 1))) + wo64, SENT64);
      }
    } else {
      if (!(n & 3)) {
        st_agent64(reinterpret_cast<unsigned long long*>(h1w + slotw(bg, t & (DEP - 1))) + wo64, dw);
        st_agent64(reinterpret_cast<unsigned long long*>(h1w + slotw(bg, (t + RST) & (DEP - 1))) + wo64, SENT64);
      }
      if (t == T_STEPS - 1)
        h1fin[(size_t)(bg * 16 + m) * HID + hid0 + n] = h;
    }
    c_state = c_new;
  }
}

__global__ __launch_bounds__(256, 1) void k_lstm(
    const unsigned short* __restrict__ x_bf,
    const float* __restrict__ w_ih0, const float* __restrict__ w_hh0,
    const float* __restrict__ b_ih0, const float* __restrict__ b_hh0,
    const float* __restrict__ w_ih1, const float* __restrict__ w_hh1,
    const float* __restrict__ b_ih1, const float* __restrict__ b_hh1,
    unsigned int* h0w, unsigned int* h1w, float* h1fin, unsigned int* flags)
{
  __shared__ float spart[2 * 4096];
  const int xg  = blockIdx.x & 7;
  const int blk = blockIdx.x >> 3;
  const int bg  = xg & 3;
  if (xg < 4)
    lstm_body<0>(x_bf, w_ih0, w_hh0, b_ih0, b_hh0, h0w, h1w, h1fin, flags, bg, blk, spart);
  else
    lstm_body<1>(x_bf, w_ih1, w_hh1, b_ih1, b_hh1, h0w, h1w, h1fin, flags, bg, blk, spart);
}

// ---------------- output head on final h1 (fp32) ----------------
__global__ __launch_bounds__(256) void k_head(
    const float* __restrict__ h1, const float* __restrict__ w1, const float* __restrict__ b1,
    const float* __restrict__ w2, const float* __restrict__ b2, float* __restrict__ out)
{
  int b = blockIdx.x, tid = threadIdx.x;
  __shared__ float sh[HID];
  __shared__ float sm[2 * HID];
  for (int k = tid; k < HID; k += 256) sh[k] = h1[(size_t)b * HID + k];
  __syncthreads();
#pragma unroll
  for (int r0 = 0; r0 < 4; ++r0) {
    int row = r0 * 256 + tid;
    const f32x4* wr = reinterpret_cast<const f32x4*>(w1 + (size_t)row * HID);
    float s = 0.f;
#pragma unroll 4
    for (int k = 0; k < HID / 4; ++k) {
      f32x4 v = wr[k];
      s += v[0] * sh[k * 4] + v[1] * sh[k * 4 + 1] + v[2] * sh[k * 4 + 2] + v[3] * sh[k * 4 + 3];
    }
    sm[row] = fmaxf(b1[row] + s, 0.f);
  }
  __syncthreads();
  if (tid < 32) {
    const f32x4* wr = reinterpret_cast<const f32x4*>(w2 + (size_t)tid * 2 * HID);
    float s = b2[tid];
#pragma unroll 4
    for (int k = 0; k < 2 * HID / 4; ++k) {
      f32x4 v = wr[k];
      s += v[0] * sm[k * 4] + v[1] * sm[k * 4 + 1] + v[2] * sm[k * 4 + 2] + v[3] * sm[k * 4 + 3];
    }
    if (tid >= 24) s = sigmoidf_(s);   // CAT_FLAGS[24:]
    out[b * 32 + tid] = s;
  }
}

extern "C" void kernel_launch(void* const* d_in, const int* in_sizes, int n_in,
                              void* d_out, int out_size, void* d_ws, size_t ws_size,
                              hipStream_t stream) {
  const float* ws_in  = (const float*)d_in[0];
  const int*   aidx   = (const int*)d_in[1];
  const float* emb    = (const float*)d_in[2];
  const float* in_w   = (const float*)d_in[3];
  const float* in_b   = (const float*)d_in[4];
  const float* w_ih0  = (const float*)d_in[5];
  const float* w_hh0  = (const float*)d_in[6];
  const float* b_ih0  = (const float*)d_in[7];
  const float* b_hh0  = (const float*)d_in[8];
  const float* w_ih1  = (const float*)d_in[9];
  const float* w_hh1  = (const float*)d_in[10];
  const float* b_ih1  = (const float*)d_in[11];
  const float* b_hh1  = (const float*)d_in[12];
  const float* out_w1 = (const float*)d_in[13];
  const float* out_b1 = (const float*)d_in[14];
  const float* out_w2 = (const float*)d_in[15];
  const float* out_b2 = (const float*)d_in[16];

  unsigned char* ws = (unsigned char*)d_ws;
  const size_t X_OFF   = 0;                        // 16,777,216
  const size_t RING_SZ = 4u * DEP * SLOTW * 4;     // 1,048,576 per ring
  const size_t H0_OFF  = 16777216;
  const size_t H1_OFF  = H0_OFF + RING_SZ;
  const size_t HF_OFF  = H1_OFF + RING_SZ;         // h1fin 131,072
  const size_t FL_OFF  = HF_OFF + 131072;          // flags 16,384
  unsigned short* x_bf  = (unsigned short*)(ws + X_OFF);
  unsigned int*   h0w   = (unsigned int*)(ws + H0_OFF);
  unsigned int*   h1w   = (unsigned int*)(ws + H1_OFF);
  float*          h1fin = (float*)(ws + HF_OFF);
  unsigned int*   flags = (unsigned int*)(ws + FL_OFF);

  hipMemsetAsync(ws + H0_OFF, 0x7F, 2 * RING_SZ, stream);  // rings -> sentinel
  hipMemsetAsync(ws + FL_OFF, 0, 16384, stream);
  k_prep<<<dim3(T_STEPS), dim3(256), 0, stream>>>(ws_in, aidx, emb, in_w, in_b, x_bf);
  k_lstm<<<dim3(256), dim3(256), 0, stream>>>(x_bf, w_ih0, w_hh0, b_ih0, b_hh0,
                                              w_ih1, w_hh1, b_ih1, b_hh1,
                                              h0w, h1w, h1fin, flags);
  k_head<<<dim3(BATCH), dim3(256), 0, stream>>>(h1fin, out_w1, out_b1, out_w2, out_b2, (float*)d_out);
}

// Round 12
// 1529.843 us; speedup vs baseline: 1.0373x; 1.0373x over previous
//
#include <hip/hip_runtime.h>

#define T_STEPS 512
#define BATCH   64
#define IN_SZ   32
#define AD      32
#define INNER   256
#define PROJ    224
#define HID     512
#define SENTW   0x7F7F7F7Fu   // bf16 0x7F7F = 3.3e38; impossible for |h|<1 outputs
#define SENT64  0x7F7F7F7F7F7F7F7FULL
#define DEP     16            // ring depth (slots per batch-group)
#define RST     6             // producer reset distance (slots ahead)
#define SLOTW   4096          // u32 words per 16KB slot

typedef __attribute__((ext_vector_type(8))) short short8;
typedef __attribute__((ext_vector_type(4))) float f32x4;

static __device__ __forceinline__ unsigned short f2bf(float f) {
  unsigned int u = __float_as_uint(f);
  u += 0x7FFFu + ((u >> 16) & 1u);
  return (unsigned short)(u >> 16);
}
static __device__ __forceinline__ float sigmoidf_(float x) { return 1.f / (1.f + __expf(-x)); }
static __device__ __forceinline__ float tanhf_(float x) {
  float e = __expf(-2.f * fabsf(x));
  float r = (1.f - e) / (1.f + e);
  return x < 0.f ? -r : r;
}

// ---------------- kernel A: x = [relu(in_w@state+in_b) | emb[idx]] bf16, [t][b][256]
__global__ __launch_bounds__(256) void k_prep(
    const float* __restrict__ ws_in, const int* __restrict__ act_idx,
    const float* __restrict__ emb, const float* __restrict__ in_w,
    const float* __restrict__ in_b, unsigned short* __restrict__ x_bf)
{
  int t = blockIdx.x;
  int tid = threadIdx.x;
  __shared__ float st[BATCH * IN_SZ];
  __shared__ int ai[BATCH];
  for (int i = tid; i < BATCH * IN_SZ; i += 256) {
    int b = i >> 5, k = i & 31;
    st[i] = ws_in[((size_t)b * T_STEPS + t) * IN_SZ + k];
  }
  if (tid < BATCH) ai[tid] = act_idx[tid * T_STEPS + t];
  __syncthreads();
  if (tid < PROJ) {
    float w[IN_SZ];
    const float* wrow = in_w + tid * IN_SZ;
#pragma unroll
    for (int k = 0; k < IN_SZ; ++k) w[k] = wrow[k];
    float bb = in_b[tid];
    for (int b = 0; b < BATCH; ++b) {
      float acc = bb;
      const float* sb = st + b * IN_SZ;
#pragma unroll
      for (int k = 0; k < IN_SZ; ++k) acc += w[k] * sb[k];
      x_bf[((size_t)t * BATCH + b) * INNER + tid] = f2bf(fmaxf(acc, 0.f));
    }
  } else {
    int j = tid - PROJ;
    for (int b = 0; b < BATCH; ++b)
      x_bf[((size_t)t * BATCH + b) * INNER + tid] = f2bf(emb[ai[b] * AD + j]);
  }
}

// ---------------- helpers ----------------
static __device__ __forceinline__ short8 bfrag_load(const float* __restrict__ w, int stride, int row, int k0) {
  const float* p = w + (size_t)row * stride + k0;
  f32x4 a = *reinterpret_cast<const f32x4*>(p);
  f32x4 b = *reinterpret_cast<const f32x4*>(p + 4);
  short8 r;
  r[0] = (short)f2bf(a[0]); r[1] = (short)f2bf(a[1]); r[2] = (short)f2bf(a[2]); r[3] = (short)f2bf(a[3]);
  r[4] = (short)f2bf(b[0]); r[5] = (short)f2bf(b[1]); r[6] = (short)f2bf(b[2]); r[7] = (short)f2bf(b[3]);
  return r;
}

struct Frag64 { unsigned long long u[8]; };   // this lane's 4 k-chunks x 16B
union FU2 { unsigned long long u[2]; short8 s; };

// load this lane's 64B (4 chunks at 1KB stride) via agent-scope relaxed atomics
static __device__ __forceinline__ void ld64(const unsigned long long* q, Frag64& f) {
#pragma unroll
  for (int kk = 0; kk < 4; ++kk) {
    f.u[kk * 2]     = __hip_atomic_load(q + kk * 128,     __ATOMIC_RELAXED, __HIP_MEMORY_SCOPE_AGENT);
    f.u[kk * 2 + 1] = __hip_atomic_load(q + kk * 128 + 1, __ATOMIC_RELAXED, __HIP_MEMORY_SCOPE_AGENT);
  }
}
static __device__ __forceinline__ bool fragok(const Frag64& f) {
  bool ok = true;
#pragma unroll
  for (int i = 0; i < 8; ++i)
    ok = ok & ((unsigned)(f.u[i] >> 32) != SENTW) & ((unsigned)f.u[i] != SENTW);
  return ok;
}
// R7's proven simple poll: re-sample until all 16 words valid; backoff after 2 misses
static __device__ __forceinline__ Frag64 poll_one(const unsigned long long* q) {
  Frag64 f;
  int miss = 0;
  while (true) {
    ld64(q, f);
    if (__all((int)fragok(f))) break;
    if (++miss > 2) __builtin_amdgcn_s_sleep(1);
  }
  return f;
}
// joint poll of two rings: single detect latency for whichever arrives last
static __device__ __forceinline__ void poll_two(const unsigned long long* qa, const unsigned long long* qb,
                                                Frag64& fa, Frag64& fb) {
  int miss = 0;
  while (true) {
    ld64(qa, fa);
    ld64(qb, fb);
    if (__all((int)(fragok(fa) & fragok(fb)))) break;
    if (++miss > 2) __builtin_amdgcn_s_sleep(1);
  }
}

static __device__ __forceinline__ void mfma4(const Frag64& f, const short8* wf, f32x4* acc) {
#pragma unroll
  for (int kk = 0; kk < 4; ++kk) {
    FU2 u; u.u[0] = f.u[kk * 2]; u.u[1] = f.u[kk * 2 + 1];
#pragma unroll
    for (int g = 0; g < 4; ++g)
      acc[g] = __builtin_amdgcn_mfma_f32_16x16x32_bf16(u.s, wf[g * 4 + kk], acc[g], 0, 0, 0);
  }
}

static __device__ __forceinline__ void st_agent(unsigned int* p, unsigned int v) {
  __hip_atomic_store(p, v, __ATOMIC_RELAXED, __HIP_MEMORY_SCOPE_AGENT);
}
static __device__ __forceinline__ void st_agent64(unsigned long long* p, unsigned long long v) {
  __hip_atomic_store(p, v, __ATOMIC_RELAXED, __HIP_MEMORY_SCOPE_AGENT);
}
static __device__ __forceinline__ size_t slotw(int bg, int d) { return ((size_t)(bg * DEP + d)) * SLOTW; }

// ---------------- persistent 2-layer LSTM ----------------
// R7 proven skeleton: 256 blocks; xg=blockIdx&7: layer=xg>=4, bg=xg&3; blk=blockIdx>>3
// owns hid [blk*16,+16). ALL cross-block traffic agent-scope data-as-flag sentinel rings
// (DEP 16, producer resets +6, zero drains); L1 consumption flags every 2 steps; L0 reuse
// guard every 4 (lag<=8 <= DEP-RST-1=9). R12 = R7 + u64-packed publishes + L0 speculative
// pre-poll + conflict-free scalar spart (the only untested combo of validated deltas).
template<int L>
static __device__ void lstm_body(
    const unsigned short* __restrict__ x_bf,
    const float* __restrict__ wih, const float* __restrict__ whh,
    const float* __restrict__ bih, const float* __restrict__ bhh,
    unsigned int* __restrict__ h0w, unsigned int* __restrict__ h1w,
    float* __restrict__ h1fin, unsigned int* __restrict__ flags,
    int bg, int blk, float* __restrict__ spart)
{
  constexpr int KI = (L == 0) ? 2 : 4;

  const int tid  = threadIdx.x;
  const int lane = tid & 63;
  const int wv   = tid >> 6;
  const int q    = lane >> 4;
  const int ln   = lane & 15;
  const int hid0 = blk << 4;
  const int m    = tid >> 4;
  const int n    = tid & 15;
  // consumer u64 base: chunk kk at +kk*128 u64 (1KB); block-major slot layout
  const int cb64 = (wv * 8 + (q >> 1)) * 64 + ln * 4 + (q & 1) * 2;

  float bias[4];
#pragma unroll
  for (int g = 0; g < 4; ++g)
    bias[g] = bih[g * HID + hid0 + n] + bhh[g * HID + hid0 + n];

  short8 fih[4 * KI];
#pragma unroll
  for (int g = 0; g < 4; ++g)
#pragma unroll
    for (int kk = 0; kk < KI; ++kk)
      fih[g * KI + kk] = bfrag_load(wih, (L == 0) ? INNER : HID,
                                    g * HID + hid0 + ln, (wv * KI + kk) * 32 + q * 8);
  short8 fhh[16];
#pragma unroll
  for (int g = 0; g < 4; ++g)
#pragma unroll
    for (int kk = 0; kk < 4; ++kk)
      fhh[g * 4 + kk] = bfrag_load(whh, HID, g * HID + hid0 + ln, (wv * 4 + kk) * 32 + q * 8);

  // producer u64 slot (lanes with n%4==0 store 4 packed h values)
  const int wo64 = blk * 64 + m * 4 + (n >> 2);
  float c_state = 0.f;

  for (int t = 0; t < T_STEPS; ++t) {
    f32x4 acc[4];
#pragma unroll
    for (int g = 0; g < 4; ++g) acc[g] = (f32x4){0.f, 0.f, 0.f, 0.f};

    if constexpr (L == 0) {
      // speculative pre-poll: issue h0[t-1] loads NOW; verify after x-MFMAs
      const unsigned long long* hq = reinterpret_cast<const unsigned long long*>(
          h0w + slotw(bg, (t - 1) & (DEP - 1))) + cb64;
      Frag64 f0;
      if (t > 0) ld64(hq, f0);

      // x-side (static, cached) — overlaps the in-flight h loads
      const unsigned short* xr = x_bf + ((size_t)t * BATCH + bg * 16 + ln) * INNER + q * 8;
#pragma unroll
      for (int kk = 0; kk < KI; ++kk) {
        short8 xa = *reinterpret_cast<const short8*>(xr + (wv * KI + kk) * 32);
#pragma unroll
        for (int g = 0; g < 4; ++g)
          acc[g] = __builtin_amdgcn_mfma_f32_16x16x32_bf16(xa, fih[g * KI + kk], acc[g], 0, 0, 0);
      }
      // ring-reuse guard vs layer 1 (every 4 steps)
      if ((t & 3) == 0 && t >= 8) {
        const unsigned int* fp = flags + (bg * 32 + (lane & 31)) * 32;
        unsigned int tgt = (unsigned)(t - 4);
        while (true) {
          unsigned int v = __hip_atomic_load(fp, __ATOMIC_RELAXED, __HIP_MEMORY_SCOPE_AGENT);
          if (__all((int)(v >= tgt))) break;
          __builtin_amdgcn_s_sleep(1);
        }
        asm volatile("" ::: "memory");
      }
      if (t > 0) {
        if (!__all((int)fragok(f0))) f0 = poll_one(hq);   // resume proven poll on miss
        mfma4(f0, fhh, acc);
      }
    } else {
      if (t > 0) {  // joint poll: h1[t-1] (self) + h0[t] (cross) in ONE detect loop
        Frag64 fa, fb;
        poll_two(reinterpret_cast<const unsigned long long*>(h1w + slotw(bg, (t - 1) & (DEP - 1))) + cb64,
                 reinterpret_cast<const unsigned long long*>(h0w + slotw(bg, t & (DEP - 1))) + cb64, fa, fb);
        mfma4(fa, fhh, acc);
        mfma4(fb, fih, acc);
      } else {
        Frag64 fb = poll_one(reinterpret_cast<const unsigned long long*>(h0w + slotw(bg, 0)) + cb64);
        mfma4(fb, fih, acc);
      }
    }

    // K-split partial exchange (R7 layout: XOR swizzle, conflict-free; dbuf, 1 barrier)
    float* sp_w = spart + (t & 1) * 4096;
#pragma unroll
    for (int g = 0; g < 4; ++g)
#pragma unroll
      for (int r = 0; r < 4; ++r)
        sp_w[(((wv * 4 + g) * 4 + r) * 4 + (q ^ r)) * 16 + ln] = acc[g][r];
    __syncthreads();

    if constexpr (L == 1) {  // consumption flag (h0[t] loads completed before barrier)
      if ((t & 1) == 1 && tid == 0)
        st_agent(flags + (bg * 32 + blk) * 32, (unsigned)(t + 1));
    }

    float gate[4];
#pragma unroll
    for (int g = 0; g < 4; ++g) {
      float s = bias[g];
#pragma unroll
      for (int w2 = 0; w2 < 4; ++w2)
        s += sp_w[(((w2 * 4 + g) * 4 + (m & 3)) * 4 + ((m >> 2) ^ (m & 3))) * 16 + n];
      gate[g] = s;
    }
    float gi = sigmoidf_(gate[0]);
    float gf = sigmoidf_(gate[1]);
    float gc = tanhf_(gate[2]);
    float go = sigmoidf_(gate[3]);
    float c_new = gf * c_state + gi * gc;
    float h = go * tanhf_(c_new);

    // publish FIRST (u64-packed: 4 h values per store), bookkeeping after
    float hp = __shfl_xor(h, 1);
    unsigned int wword = (unsigned)f2bf(h) | ((unsigned)f2bf(hp) << 16);
    unsigned int wy = __shfl_down(wword, 2);
    unsigned long long dw = (unsigned long long)wword | ((unsigned long long)wy << 32);
    if constexpr (L == 0) {
      if (!(n & 3)) {
        st_agent64(reinterpret_cast<unsigned long long*>(h0w + slotw(bg, t & (DEP - 1))) + wo64, dw);
        st_agent64(reinterpret_cast<unsigned long long*>(h0w + slotw(bg, (t + RST) & (DEP - 1))) + wo64, SENT64);
      }
    } else {
      if (!(n & 3)) {
        st_agent64(reinterpret_cast<unsigned long long*>(h1w + slotw(bg, t & (DEP - 1))) + wo64, dw);
        st_agent64(reinterpret_cast<unsigned long long*>(h1w + slotw(bg, (t + RST) & (DEP - 1))) + wo64, SENT64);
      }
      if (t == T_STEPS - 1)
        h1fin[(size_t)(bg * 16 + m) * HID + hid0 + n] = h;
    }
    c_state = c_new;
  }
}

__global__ __launch_bounds__(256, 1) void k_lstm(
    const unsigned short* __restrict__ x_bf,
    const float* __restrict__ w_ih0, const float* __restrict__ w_hh0,
    const float* __restrict__ b_ih0, const float* __restrict__ b_hh0,
    const float* __restrict__ w_ih1, const float* __restrict__ w_hh1,
    const float* __restrict__ b_ih1, const float* __restrict__ b_hh1,
    unsigned int* h0w, unsigned int* h1w, float* h1fin, unsigned int* flags)
{
  __shared__ float spart[2 * 4096];
  const int xg  = blockIdx.x & 7;
  const int blk = blockIdx.x >> 3;
  const int bg  = xg & 3;
  if (xg < 4)
    lstm_body<0>(x_bf, w_ih0, w_hh0, b_ih0, b_hh0, h0w, h1w, h1fin, flags, bg, blk, spart);
  else
    lstm_body<1>(x_bf, w_ih1, w_hh1, b_ih1, b_hh1, h0w, h1w, h1fin, flags, bg, blk, spart);
}

// ---------------- output head on final h1 (fp32) ----------------
__global__ __launch_bounds__(256) void k_head(
    const float* __restrict__ h1, const float* __restrict__ w1, const float* __restrict__ b1,
    const float* __restrict__ w2, const float* __restrict__ b2, float* __restrict__ out)
{
  int b = blockIdx.x, tid = threadIdx.x;
  __shared__ float sh[HID];
  __shared__ float sm[2 * HID];
  for (int k = tid; k < HID; k += 256) sh[k] = h1[(size_t)b * HID + k];
  __syncthreads();
#pragma unroll
  for (int r0 = 0; r0 < 4; ++r0) {
    int row = r0 * 256 + tid;
    const f32x4* wr = reinterpret_cast<const f32x4*>(w1 + (size_t)row * HID);
    float s = 0.f;
#pragma unroll 4
    for (int k = 0; k < HID / 4; ++k) {
      f32x4 v = wr[k];
      s += v[0] * sh[k * 4] + v[1] * sh[k * 4 + 1] + v[2] * sh[k * 4 + 2] + v[3] * sh[k * 4 + 3];
    }
    sm[row] = fmaxf(b1[row] + s, 0.f);
  }
  __syncthreads();
  if (tid < 32) {
    const f32x4* wr = reinterpret_cast<const f32x4*>(w2 + (size_t)tid * 2 * HID);
    float s = b2[tid];
#pragma unroll 4
    for (int k = 0; k < 2 * HID / 4; ++k) {
      f32x4 v = wr[k];
      s += v[0] * sm[k * 4] + v[1] * sm[k * 4 + 1] + v[2] * sm[k * 4 + 2] + v[3] * sm[k * 4 + 3];
    }
    if (tid >= 24) s = sigmoidf_(s);   // CAT_FLAGS[24:]
    out[b * 32 + tid] = s;
  }
}

extern "C" void kernel_launch(void* const* d_in, const int* in_sizes, int n_in,
                              void* d_out, int out_size, void* d_ws, size_t ws_size,
                              hipStream_t stream) {
  const float* ws_in  = (const float*)d_in[0];
  const int*   aidx   = (const int*)d_in[1];
  const float* emb    = (const float*)d_in[2];
  const float* in_w   = (const float*)d_in[3];
  const float* in_b   = (const float*)d_in[4];
  const float* w_ih0  = (const float*)d_in[5];
  const float* w_hh0  = (const float*)d_in[6];
  const float* b_ih0  = (const float*)d_in[7];
  const float* b_hh0  = (const float*)d_in[8];
  const float* w_ih1  = (const float*)d_in[9];
  const float* w_hh1  = (const float*)d_in[10];
  const float* b_ih1  = (const float*)d_in[11];
  const float* b_hh1  = (const float*)d_in[12];
  const float* out_w1 = (const float*)d_in[13];
  const float* out_b1 = (const float*)d_in[14];
  const float* out_w2 = (const float*)d_in[15];
  const float* out_b2 = (const float*)d_in[16];

  unsigned char* ws = (unsigned char*)d_ws;
  const size_t X_OFF   = 0;                        // 16,777,216
  const size_t RING_SZ = 4u * DEP * SLOTW * 4;     // 1,048,576 per ring
  const size_t H0_OFF  = 16777216;
  const size_t H1_OFF  = H0_OFF + RING_SZ;
  const size_t HF_OFF  = H1_OFF + RING_SZ;         // h1fin 131,072
  const size_t FL_OFF  = HF_OFF + 131072;          // flags 16,384
  unsigned short* x_bf  = (unsigned short*)(ws + X_OFF);
  unsigned int*   h0w   = (unsigned int*)(ws + H0_OFF);
  unsigned int*   h1w   = (unsigned int*)(ws + H1_OFF);
  float*          h1fin = (float*)(ws + HF_OFF);
  unsigned int*   flags = (unsigned int*)(ws + FL_OFF);

  hipMemsetAsync(ws + H0_OFF, 0x7F, 2 * RING_SZ, stream);  // rings -> sentinel
  hipMemsetAsync(ws + FL_OFF, 0, 16384, stream);
  k_prep<<<dim3(T_STEPS), dim3(256), 0, stream>>>(ws_in, aidx, emb, in_w, in_b, x_bf);
  k_lstm<<<dim3(256), dim3(256), 0, stream>>>(x_bf, w_ih0, w_hh0, b_ih0, b_hh0,
                                              w_ih1, w_hh1, b_ih1, b_hh1,
                                              h0w, h1w, h1fin, flags);
  k_head<<<dim3(BATCH), dim3(256), 0, stream>>>(h1fin, out_w1, out_b1, out_w2, out_b2, (float*)d_out);
}